// Round 1
// baseline (278.198 us; speedup 1.0000x reference)
//
#include <hip/hip_runtime.h>
#include <stdint.h>

#define PTS    256                  // points per block (== blockDim.x)
#define DIM    10
#define STRIDE 11                   // LDS pad: 11 coprime with 32 banks -> <=2-way (free)
#define NVEC   ((PTS * DIM) / 4)    // 640 float4 per block chunk

// Codebook is a compile-time constant (+-1 entries). __device__ constexpr:
// folds to add/sub chains in the unrolled dot loop, and lives in .rodata for
// the runtime-indexed gather in the epilogue.
__device__ constexpr float CB[32][10] = {
 {-1,-1,-1,-1,-1,-1,-1,-1,-1,-1},{-1,-1,-1,-1,1,1,-1,-1,-1,1},{-1,-1,-1,1,-1,-1,-1,-1,1,1},{-1,-1,-1,1,1,1,-1,-1,1,-1},
 {-1,-1,1,-1,-1,-1,-1,1,1,-1},{-1,-1,1,-1,1,1,-1,1,1,1},{-1,-1,1,1,-1,-1,-1,1,-1,1},{-1,-1,1,1,1,1,-1,1,-1,-1},
 {-1,1,-1,-1,-1,-1,1,1,-1,-1},{-1,1,-1,-1,1,1,1,1,-1,1},{-1,1,-1,1,-1,-1,1,1,1,1},{-1,1,-1,1,1,1,1,1,1,-1},
 {-1,1,1,-1,-1,-1,1,-1,1,-1},{-1,1,1,-1,1,1,1,-1,1,1},{-1,1,1,1,-1,-1,1,-1,-1,1},{-1,1,1,1,1,1,1,-1,-1,-1},
 {1,-1,-1,-1,-1,1,1,-1,-1,-1},{1,-1,-1,-1,1,-1,1,-1,-1,1},{1,-1,-1,1,-1,1,1,-1,1,1},{1,-1,-1,1,1,-1,1,-1,1,-1},
 {1,-1,1,-1,-1,1,1,1,1,-1},{1,-1,1,-1,1,-1,1,1,1,1},{1,-1,1,1,-1,1,1,1,-1,1},{1,-1,1,1,1,-1,1,1,-1,-1},
 {1,1,-1,-1,-1,1,-1,1,-1,-1},{1,1,-1,-1,1,-1,-1,1,-1,1},{1,1,-1,1,-1,1,-1,1,1,1},{1,1,-1,1,1,-1,-1,1,1,-1},
 {1,1,1,-1,-1,1,-1,-1,1,-1},{1,1,1,-1,1,-1,-1,-1,1,1},{1,1,1,1,-1,1,-1,-1,-1,1},{1,1,1,1,1,-1,-1,-1,-1,-1}};

__global__ __launch_bounds__(PTS) void softdec_kernel(
    const float* __restrict__ sig, float* __restrict__ out)
{
    __shared__ float sIn [PTS * STRIDE];
    __shared__ float sOut[PTS * STRIDE];
    const int tid = threadIdx.x;
    const size_t base = (size_t)blockIdx.x * (PTS * DIM);   // flat float offset

    // ---- stage in: coalesced float4 loads -> padded LDS ----
    const float4* __restrict__ gin = (const float4*)(sig + base);
    #pragma unroll
    for (int it = 0; it < 3; ++it) {
        const int i = tid + it * PTS;       // 0..767, valid < 640
        if (i < NVEC) {
            const float4 v = gin[i];
            const float vv[4] = {v.x, v.y, v.z, v.w};
            #pragma unroll
            for (int j = 0; j < 4; ++j) {
                const int gg = i * 4 + j;
                const int p  = gg / DIM;            // magic-mul div by 10
                const int c  = gg - p * DIM;
                sIn[p * STRIDE + c] = vv[j];
            }
        }
    }
    __syncthreads();

    // ---- per-thread: load point, 32 signed sums, argmax (first-index ties) ----
    float x[DIM];
    #pragma unroll
    for (int j = 0; j < DIM; ++j) x[j] = sIn[tid * STRIDE + j];

    float best = -1e30f;
    int   bi   = 0;
    #pragma unroll
    for (int k = 0; k < 32; ++k) {
        float s = 0.0f;
        #pragma unroll
        for (int j = 0; j < DIM; ++j)
            s = (CB[k][j] > 0.0f) ? (s + x[j]) : (s - x[j]);  // folds to add/sub
        if (s > best) { best = s; bi = k; }   // strict > keeps lowest index on tie
    }

    // ---- write winning codeword into padded LDS ----
    #pragma unroll
    for (int j = 0; j < DIM; ++j)
        sOut[tid * STRIDE + j] = CB[bi][j];
    __syncthreads();

    // ---- stage out: padded LDS -> coalesced float4 stores ----
    float4* __restrict__ gout = (float4*)(out + base);
    #pragma unroll
    for (int it = 0; it < 3; ++it) {
        const int i = tid + it * PTS;
        if (i < NVEC) {
            float4 v;
            float* vv = (float*)&v;
            #pragma unroll
            for (int j = 0; j < 4; ++j) {
                const int gg = i * 4 + j;
                const int p  = gg / DIM;
                const int c  = gg - p * DIM;
                vv[j] = sOut[p * STRIDE + c];
            }
            gout[i] = v;
        }
    }
}

extern "C" void kernel_launch(void* const* d_in, const int* in_sizes, int n_in,
                              void* d_out, int out_size, void* d_ws, size_t ws_size,
                              hipStream_t stream) {
    const float* sig = (const float*)d_in[0];
    float* out = (float*)d_out;
    const int total  = in_sizes[0];        // B*N*D = 41,943,040
    const int pts    = total / DIM;        // 4,194,304
    const int blocks = pts / PTS;          // 16,384 (exact)
    softdec_kernel<<<blocks, PTS, 0, stream>>>(sig, out);
}